// Round 3
// baseline (3017.500 us; speedup 1.0000x reference)
//
#include <hip/hip_runtime.h>

// Problem constants (match reference)
#define NN 100000
#define EE 1600000
#define FDIM 128
#define EPS 1e-5f

#define ROWS 64     // rows per block in ln_gemm
#define LDX 132     // padded LDS stride (floats) for xn tile
#define LDW 132     // padded LDS stride (floats) for W^T tile

// ---------------- degree ----------------
__global__ __launch_bounds__(256) void k_deg_init(float* __restrict__ deg) {
    int i = blockIdx.x * 256 + threadIdx.x;
    if (i < NN) deg[i] = 1.0f;  // self-loop weight
}

__global__ __launch_bounds__(256) void k_deg_acc(const int* __restrict__ col,
                                                 const float* __restrict__ ew,
                                                 float* __restrict__ deg) {
    int e = blockIdx.x * 256 + threadIdx.x;
    if (e < EE) atomicAdd(&deg[col[e]], ew[e]);
}

// ---------------- LN + ReLU + GEMM (h = relu(LN(x)) @ W^T) ----------------
__global__ __launch_bounds__(256) void k_ln_gemm(const float* __restrict__ x,
                                                 const float* __restrict__ gamma,
                                                 const float* __restrict__ beta,
                                                 const float* __restrict__ W,
                                                 float* __restrict__ h) {
    __shared__ float sWt[128 * LDW];   // W transposed: sWt[k][f] = W[f][k]
    __shared__ float sXn[ROWS * LDX];  // normalized rows

    int t = threadIdx.x;
    int lane = t & 63;
    int wv = t >> 6;
    int row0 = blockIdx.x * ROWS;

    // Stage W^T into LDS (coalesced global read; 8-way LDS write conflict, once/block)
    for (int idx = t; idx < 128 * 128; idx += 256) {
        int f = idx >> 7, k = idx & 127;
        sWt[k * LDW + f] = W[idx];
    }

    // LayerNorm + ReLU: each wave handles 16 rows
    float g0 = gamma[lane * 2], g1 = gamma[lane * 2 + 1];
    float b0 = beta[lane * 2],  b1 = beta[lane * 2 + 1];
    for (int i = 0; i < 16; ++i) {
        int r = wv + i * 4;          // local row
        int row = row0 + r;
        float2 v = make_float2(0.f, 0.f);
        if (row < NN) v = *(const float2*)&x[row * FDIM + lane * 2];
        float s  = v.x + v.y;
        float sq = v.x * v.x + v.y * v.y;
        #pragma unroll
        for (int d = 1; d < 64; d <<= 1) {
            s  += __shfl_xor(s, d, 64);
            sq += __shfl_xor(sq, d, 64);
        }
        float mean = s * (1.0f / 128.0f);
        float var  = sq * (1.0f / 128.0f) - mean * mean;
        float rstd = rsqrtf(var + EPS);
        float xn0 = fmaxf((v.x - mean) * rstd * g0 + b0, 0.f);
        float xn1 = fmaxf((v.y - mean) * rstd * g1 + b1, 0.f);
        if (row >= NN) { xn0 = 0.f; xn1 = 0.f; }
        *(float2*)&sXn[r * LDX + lane * 2] = make_float2(xn0, xn1);
    }
    __syncthreads();

    // GEMM: each thread computes 8 rows x 4 cols
    int c0 = (t & 31) * 4;
    int r0 = (t >> 5) * 8;
    float acc[8][4];
    #pragma unroll
    for (int i = 0; i < 8; i++)
        #pragma unroll
        for (int j = 0; j < 4; j++) acc[i][j] = 0.f;

    for (int k0 = 0; k0 < 128; k0 += 4) {
        float w4[4][4];
        #pragma unroll
        for (int kk = 0; kk < 4; kk++) {
            float4 wv4 = *(const float4*)&sWt[(k0 + kk) * LDW + c0];
            w4[kk][0] = wv4.x; w4[kk][1] = wv4.y; w4[kk][2] = wv4.z; w4[kk][3] = wv4.w;
        }
        #pragma unroll
        for (int i = 0; i < 8; i++) {
            float4 xv = *(const float4*)&sXn[(r0 + i) * LDX + k0];
            float xk[4] = {xv.x, xv.y, xv.z, xv.w};
            #pragma unroll
            for (int kk = 0; kk < 4; kk++)
                #pragma unroll
                for (int j = 0; j < 4; j++)
                    acc[i][j] = fmaf(xk[kk], w4[kk][j], acc[i][j]);
        }
    }

    #pragma unroll
    for (int i = 0; i < 8; i++) {
        int row = row0 + r0 + i;
        if (row < NN) {
            float4 o = make_float4(acc[i][0], acc[i][1], acc[i][2], acc[i][3]);
            *(float4*)&h[row * FDIM + c0] = o;
        }
    }
}

// ---------------- out = h / deg + b  (self-loop + bias) ----------------
__global__ __launch_bounds__(256) void k_init_out(const float* __restrict__ h,
                                                  const float* __restrict__ deg,
                                                  const float* __restrict__ b,
                                                  float* __restrict__ out) {
    int i = blockIdx.x * 256 + threadIdx.x;  // one float4 each
    if (i < NN * 32) {
        int row = i >> 5, f0 = (i & 31) * 4;
        float d = deg[row];
        float inv = d > 0.f ? 1.0f / d : 0.f;   // dinv * 1.0 * dinv
        float4 hv = *(const float4*)&h[row * FDIM + f0];
        float4 bv = *(const float4*)&b[f0];
        float4 o;
        o.x = hv.x * inv + bv.x;
        o.y = hv.y * inv + bv.y;
        o.z = hv.z * inv + bv.z;
        o.w = hv.w * inv + bv.w;
        *(float4*)&out[row * FDIM + f0] = o;
    }
}

// ---------------- edge scatter: out[col] += h[row] * norm ----------------
__global__ __launch_bounds__(256) void k_scatter(const int* __restrict__ rowi,
                                                 const int* __restrict__ coli,
                                                 const float* __restrict__ ew,
                                                 const float* __restrict__ deg,
                                                 const float* __restrict__ h,
                                                 float* __restrict__ out) {
    long long gt = (long long)blockIdx.x * 256 + threadIdx.x;
    long long e = gt >> 5;                 // 32 threads per edge
    if (e < EE) {
        int f0 = ((int)gt & 31) * 4;
        int r = rowi[e], c = coli[e];
        float w = ew[e];
        float dr = deg[r], dc = deg[c];
        float norm = (dr > 0.f ? rsqrtf(dr) : 0.f) * w * (dc > 0.f ? rsqrtf(dc) : 0.f);
        float4 hv = *(const float4*)&h[r * FDIM + f0];
        float* op = &out[c * FDIM + f0];
        atomicAdd(op + 0, hv.x * norm);
        atomicAdd(op + 1, hv.y * norm);
        atomicAdd(op + 2, hv.z * norm);
        atomicAdd(op + 3, hv.w * norm);
    }
}

extern "C" void kernel_launch(void* const* d_in, const int* in_sizes, int n_in,
                              void* d_out, int out_size, void* d_ws, size_t ws_size,
                              hipStream_t stream) {
    const float* x     = (const float*)d_in[0];
    const int*   ei    = (const int*)d_in[1];    // [2,E]: rows at ei, cols at ei+EE
    const float* ew    = (const float*)d_in[2];
    const float* gamma = (const float*)d_in[3];
    const float* beta  = (const float*)d_in[4];
    const float* W     = (const float*)d_in[5];
    const float* b     = (const float*)d_in[6];
    float* out = (float*)d_out;

    // workspace: h [N*128 f32] then deg [N f32]  (~49.2 MB needed)
    float* h   = (float*)d_ws;
    float* deg = (float*)((char*)d_ws + (size_t)NN * FDIM * sizeof(float));

    hipLaunchKernelGGL(k_deg_init, dim3((NN + 255) / 256), dim3(256), 0, stream, deg);
    hipLaunchKernelGGL(k_deg_acc, dim3((EE + 255) / 256), dim3(256), 0, stream,
                       ei + EE, ew, deg);
    hipLaunchKernelGGL(k_ln_gemm, dim3((NN + ROWS - 1) / ROWS), dim3(256), 0, stream,
                       x, gamma, beta, W, h);
    hipLaunchKernelGGL(k_init_out, dim3((NN * 32 + 255) / 256), dim3(256), 0, stream,
                       h, deg, b, out);
    hipLaunchKernelGGL(k_scatter, dim3((int)(((long long)EE * 32) / 256)), dim3(256), 0, stream,
                       ei, ei + EE, ew, deg, h, out);
}

// Round 4
// 645.218 us; speedup vs baseline: 4.6767x; 4.6767x over previous
//
#include <hip/hip_runtime.h>

// Problem constants (match reference)
#define NN 100000
#define EE 1600000
#define FDIM 128
#define EPS 1e-5f

#define ROWS 64     // rows per block in ln_gemm
#define LDX 132     // padded LDS stride (floats) for xn tile
#define LDW 132     // padded LDS stride (floats) for W^T tile

#define NB1 ((NN + 255) / 256)   // 391 blocks for per-node scan

// ---------------- degree + in-degree count ----------------
__global__ __launch_bounds__(256) void k_deg_init(float* __restrict__ deg,
                                                  int* __restrict__ cnt) {
    int i = blockIdx.x * 256 + threadIdx.x;
    if (i < NN) { deg[i] = 1.0f; cnt[i] = 0; }  // self-loop weight 1.0
}

__global__ __launch_bounds__(256) void k_deg_acc(const int* __restrict__ col,
                                                 const float* __restrict__ ew,
                                                 float* __restrict__ deg,
                                                 int* __restrict__ cnt) {
    int e = blockIdx.x * 256 + threadIdx.x;
    if (e < EE) {
        int c = col[e];
        atomicAdd(&deg[c], ew[e]);
        atomicAdd(&cnt[c], 1);
    }
}

// ---------------- prefix scan (3 kernels) ----------------
__global__ __launch_bounds__(256) void k_scan1(const int* __restrict__ cnt,
                                               int* __restrict__ rowptr,
                                               int* __restrict__ bsum) {
    __shared__ int tmp[256];
    int tid = threadIdx.x;
    int i = blockIdx.x * 256 + tid;
    int v = (i < NN) ? cnt[i] : 0;
    tmp[tid] = v;
    __syncthreads();
    #pragma unroll
    for (int d = 1; d < 256; d <<= 1) {
        int t = (tid >= d) ? tmp[tid - d] : 0;
        __syncthreads();
        tmp[tid] += t;
        __syncthreads();
    }
    if (i < NN) rowptr[i] = tmp[tid] - v;          // exclusive within block
    if (tid == 255) bsum[blockIdx.x] = tmp[255];   // block total
}

__global__ __launch_bounds__(512) void k_scan2(int* __restrict__ bsum,
                                               int* __restrict__ bsumoff) {
    __shared__ int tmp[512];
    int tid = threadIdx.x;
    int v = (tid < NB1) ? bsum[tid] : 0;
    tmp[tid] = v;
    __syncthreads();
    #pragma unroll
    for (int d = 1; d < 512; d <<= 1) {
        int t = (tid >= d) ? tmp[tid - d] : 0;
        __syncthreads();
        tmp[tid] += t;
        __syncthreads();
    }
    if (tid < NB1) bsumoff[tid] = tmp[tid] - v;    // exclusive block offsets
}

__global__ __launch_bounds__(256) void k_scan3(int* __restrict__ rowptr,
                                               const int* __restrict__ bsumoff,
                                               int* __restrict__ cursor) {
    int i = blockIdx.x * 256 + threadIdx.x;
    if (i < NN) {
        rowptr[i] += bsumoff[blockIdx.x];
        cursor[i] = 0;
    }
}

// ---------------- fill CSR: sv[pos] = (src, norm) ----------------
__global__ __launch_bounds__(256) void k_fill(const int* __restrict__ rowi,
                                              const int* __restrict__ coli,
                                              const float* __restrict__ ew,
                                              const float* __restrict__ deg,
                                              const int* __restrict__ rowptr,
                                              int* __restrict__ cursor,
                                              int2* __restrict__ sv) {
    int e = blockIdx.x * 256 + threadIdx.x;
    if (e < EE) {
        int r = rowi[e], c = coli[e];
        float w = ew[e];
        float dr = deg[r], dc = deg[c];
        float norm = (dr > 0.f ? rsqrtf(dr) : 0.f) * w * (dc > 0.f ? rsqrtf(dc) : 0.f);
        int pos = rowptr[c] + atomicAdd(&cursor[c], 1);
        sv[pos] = make_int2(r, __float_as_int(norm));
    }
}

// ---------------- gather: one wave per destination node ----------------
__global__ __launch_bounds__(256) void k_gather(const float* __restrict__ h,
                                                const float* __restrict__ deg,
                                                const int* __restrict__ rowptr,
                                                const int* __restrict__ cnt,
                                                const int2* __restrict__ sv,
                                                const float* __restrict__ b,
                                                float* __restrict__ out) {
    int wv = threadIdx.x >> 6;
    int lane = threadIdx.x & 63;
    int n = blockIdx.x * 4 + wv;
    if (n >= NN) return;

    int f0 = lane * 2;
    // self-loop: dinv * 1.0 * dinv = 1/deg
    float d = deg[n];
    float inv = d > 0.f ? 1.0f / d : 0.f;
    float2 hv = *(const float2*)&h[(size_t)n * FDIM + f0];
    float accx = hv.x * inv, accy = hv.y * inv;

    int start = rowptr[n];
    int end = start + cnt[n];
    for (int j = start; j < end; ++j) {
        int2 s = sv[j];                               // broadcast load (uniform addr)
        float v = __int_as_float(s.y);
        float2 hs = *(const float2*)&h[(size_t)s.x * FDIM + f0];
        accx = fmaf(hs.x, v, accx);
        accy = fmaf(hs.y, v, accy);
    }
    float2 bv = *(const float2*)&b[f0];
    *(float2*)&out[(size_t)n * FDIM + f0] = make_float2(accx + bv.x, accy + bv.y);
}

// ---------------- LN + ReLU + GEMM (h = relu(LN(x)) @ W^T) ----------------
__global__ __launch_bounds__(256) void k_ln_gemm(const float* __restrict__ x,
                                                 const float* __restrict__ gamma,
                                                 const float* __restrict__ beta,
                                                 const float* __restrict__ W,
                                                 float* __restrict__ h) {
    __shared__ float sWt[128 * LDW];   // W transposed: sWt[k][f] = W[f][k]
    __shared__ float sXn[ROWS * LDX];  // normalized rows

    int t = threadIdx.x;
    int lane = t & 63;
    int wv = t >> 6;
    int row0 = blockIdx.x * ROWS;

    for (int idx = t; idx < 128 * 128; idx += 256) {
        int f = idx >> 7, k = idx & 127;
        sWt[k * LDW + f] = W[idx];
    }

    float g0 = gamma[lane * 2], g1 = gamma[lane * 2 + 1];
    float b0 = beta[lane * 2],  b1 = beta[lane * 2 + 1];
    for (int i = 0; i < 16; ++i) {
        int r = wv + i * 4;
        int row = row0 + r;
        float2 v = make_float2(0.f, 0.f);
        if (row < NN) v = *(const float2*)&x[row * FDIM + lane * 2];
        float s  = v.x + v.y;
        float sq = v.x * v.x + v.y * v.y;
        #pragma unroll
        for (int d = 1; d < 64; d <<= 1) {
            s  += __shfl_xor(s, d, 64);
            sq += __shfl_xor(sq, d, 64);
        }
        float mean = s * (1.0f / 128.0f);
        float var  = sq * (1.0f / 128.0f) - mean * mean;
        float rstd = rsqrtf(var + EPS);
        float xn0 = fmaxf((v.x - mean) * rstd * g0 + b0, 0.f);
        float xn1 = fmaxf((v.y - mean) * rstd * g1 + b1, 0.f);
        if (row >= NN) { xn0 = 0.f; xn1 = 0.f; }
        *(float2*)&sXn[r * LDX + lane * 2] = make_float2(xn0, xn1);
    }
    __syncthreads();

    int c0 = (t & 31) * 4;
    int r0 = (t >> 5) * 8;
    float acc[8][4];
    #pragma unroll
    for (int i = 0; i < 8; i++)
        #pragma unroll
        for (int j = 0; j < 4; j++) acc[i][j] = 0.f;

    for (int k0 = 0; k0 < 128; k0 += 4) {
        float w4[4][4];
        #pragma unroll
        for (int kk = 0; kk < 4; kk++) {
            float4 wv4 = *(const float4*)&sWt[(k0 + kk) * LDW + c0];
            w4[kk][0] = wv4.x; w4[kk][1] = wv4.y; w4[kk][2] = wv4.z; w4[kk][3] = wv4.w;
        }
        #pragma unroll
        for (int i = 0; i < 8; i++) {
            float4 xv = *(const float4*)&sXn[(r0 + i) * LDX + k0];
            float xk[4] = {xv.x, xv.y, xv.z, xv.w};
            #pragma unroll
            for (int kk = 0; kk < 4; kk++)
                #pragma unroll
                for (int j = 0; j < 4; j++)
                    acc[i][j] = fmaf(xk[kk], w4[kk][j], acc[i][j]);
        }
    }

    #pragma unroll
    for (int i = 0; i < 8; i++) {
        int row = row0 + r0 + i;
        if (row < NN) {
            float4 o = make_float4(acc[i][0], acc[i][1], acc[i][2], acc[i][3]);
            *(float4*)&h[row * FDIM + c0] = o;
        }
    }
}

// ---------------- fallback path (atomic scatter), if ws too small ----------
__global__ __launch_bounds__(256) void k_init_out(const float* __restrict__ h,
                                                  const float* __restrict__ deg,
                                                  const float* __restrict__ b,
                                                  float* __restrict__ out) {
    int i = blockIdx.x * 256 + threadIdx.x;
    if (i < NN * 32) {
        int row = i >> 5, f0 = (i & 31) * 4;
        float d = deg[row];
        float inv = d > 0.f ? 1.0f / d : 0.f;
        float4 hv = *(const float4*)&h[row * FDIM + f0];
        float4 bv = *(const float4*)&b[f0];
        float4 o;
        o.x = hv.x * inv + bv.x;
        o.y = hv.y * inv + bv.y;
        o.z = hv.z * inv + bv.z;
        o.w = hv.w * inv + bv.w;
        *(float4*)&out[row * FDIM + f0] = o;
    }
}

__global__ __launch_bounds__(256) void k_scatter(const int* __restrict__ rowi,
                                                 const int* __restrict__ coli,
                                                 const float* __restrict__ ew,
                                                 const float* __restrict__ deg,
                                                 const float* __restrict__ h,
                                                 float* __restrict__ out) {
    long long gt = (long long)blockIdx.x * 256 + threadIdx.x;
    long long e = gt >> 5;
    if (e < EE) {
        int f0 = ((int)gt & 31) * 4;
        int r = rowi[e], c = coli[e];
        float w = ew[e];
        float dr = deg[r], dc = deg[c];
        float norm = (dr > 0.f ? rsqrtf(dr) : 0.f) * w * (dc > 0.f ? rsqrtf(dc) : 0.f);
        float4 hv = *(const float4*)&h[r * FDIM + f0];
        float* op = &out[c * FDIM + f0];
        atomicAdd(op + 0, hv.x * norm);
        atomicAdd(op + 1, hv.y * norm);
        atomicAdd(op + 2, hv.z * norm);
        atomicAdd(op + 3, hv.w * norm);
    }
}

extern "C" void kernel_launch(void* const* d_in, const int* in_sizes, int n_in,
                              void* d_out, int out_size, void* d_ws, size_t ws_size,
                              hipStream_t stream) {
    const float* x     = (const float*)d_in[0];
    const int*   ei    = (const int*)d_in[1];    // [2,E]: rows at ei, cols at ei+EE
    const float* ew    = (const float*)d_in[2];
    const float* gamma = (const float*)d_in[3];
    const float* beta  = (const float*)d_in[4];
    const float* W     = (const float*)d_in[5];
    const float* b     = (const float*)d_in[6];
    float* out = (float*)d_out;

    // workspace layout (all 16B-aligned)
    char* p = (char*)d_ws;
    size_t off = 0;
    float* h      = (float*)(p + off); off += (size_t)NN * FDIM * sizeof(float); // 51.2 MB
    float* deg    = (float*)(p + off); off += (size_t)NN * sizeof(float);        // 0.4 MB
    int*   cnt    = (int*)  (p + off); off += (size_t)NN * sizeof(int);          // 0.4 MB
    int*   cursor = (int*)  (p + off); off += (size_t)NN * sizeof(int);          // 0.4 MB
    int*   rowptr = (int*)  (p + off); off += ((size_t)NN * sizeof(int) + 16);   // 0.4 MB
    int*   bsum   = (int*)  (p + off); off += 512 * sizeof(int);
    int*   bsumof = (int*)  (p + off); off += 512 * sizeof(int);
    int2*  sv     = (int2*) (p + off); off += (size_t)EE * sizeof(int2);         // 12.8 MB
    bool csr_ok = (off <= ws_size);

    hipLaunchKernelGGL(k_deg_init, dim3(NB1), dim3(256), 0, stream, deg, cnt);
    hipLaunchKernelGGL(k_deg_acc, dim3((EE + 255) / 256), dim3(256), 0, stream,
                       ei + EE, ew, deg, cnt);
    hipLaunchKernelGGL(k_ln_gemm, dim3((NN + ROWS - 1) / ROWS), dim3(256), 0, stream,
                       x, gamma, beta, W, h);

    if (csr_ok) {
        hipLaunchKernelGGL(k_scan1, dim3(NB1), dim3(256), 0, stream, cnt, rowptr, bsum);
        hipLaunchKernelGGL(k_scan2, dim3(1), dim3(512), 0, stream, bsum, bsumof);
        hipLaunchKernelGGL(k_scan3, dim3(NB1), dim3(256), 0, stream, rowptr, bsumof, cursor);
        hipLaunchKernelGGL(k_fill, dim3((EE + 255) / 256), dim3(256), 0, stream,
                           ei, ei + EE, ew, deg, rowptr, cursor, sv);
        hipLaunchKernelGGL(k_gather, dim3((NN + 3) / 4), dim3(256), 0, stream,
                           h, deg, rowptr, cnt, sv, b, out);
    } else {
        hipLaunchKernelGGL(k_init_out, dim3((NN * 32 + 255) / 256), dim3(256), 0, stream,
                           h, deg, b, out);
        hipLaunchKernelGGL(k_scatter, dim3((int)(((long long)EE * 32) / 256)), dim3(256), 0, stream,
                           ei, ei + EE, ew, deg, h, out);
    }
}

// Round 11
// 542.580 us; speedup vs baseline: 5.5614x; 1.1892x over previous
//
#include <hip/hip_runtime.h>

// Problem constants (match reference)
#define NN 100000
#define EE 1600000
#define FDIM 128
#define EPS 1e-5f

#define NB1 ((NN + 255) / 256)   // 391 blocks for per-node scan

typedef __attribute__((ext_vector_type(8))) short s16x8;   // 8 bf16 (4 VGPRs)
typedef __attribute__((ext_vector_type(4))) float f32x4;   // MFMA accumulator

__device__ __forceinline__ unsigned short f2bf(float f) {   // RNE f32->bf16
    unsigned int u = __float_as_uint(f);
    unsigned int r = u + 0x7FFFu + ((u >> 16) & 1u);
    return (unsigned short)(r >> 16);
}

// ---------------- degree + in-degree count ----------------
__global__ __launch_bounds__(256) void k_deg_init(float* __restrict__ deg,
                                                  int* __restrict__ cnt) {
    int i = blockIdx.x * 256 + threadIdx.x;
    if (i < NN) { deg[i] = 1.0f; cnt[i] = 0; }  // self-loop weight 1.0
}

__global__ __launch_bounds__(256) void k_deg_acc(const int* __restrict__ col,
                                                 const float* __restrict__ ew,
                                                 float* __restrict__ deg,
                                                 int* __restrict__ cnt) {
    int e = blockIdx.x * 256 + threadIdx.x;
    if (e < EE) {
        int c = col[e];
        atomicAdd(&deg[c], ew[e]);
        atomicAdd(&cnt[c], 1);
    }
}

// ---------------- prefix scan (3 kernels) ----------------
__global__ __launch_bounds__(256) void k_scan1(const int* __restrict__ cnt,
                                               int* __restrict__ rowptr,
                                               int* __restrict__ bsum) {
    __shared__ int tmp[256];
    int tid = threadIdx.x;
    int i = blockIdx.x * 256 + tid;
    int v = (i < NN) ? cnt[i] : 0;
    tmp[tid] = v;
    __syncthreads();
    #pragma unroll
    for (int d = 1; d < 256; d <<= 1) {
        int t = (tid >= d) ? tmp[tid - d] : 0;
        __syncthreads();
        tmp[tid] += t;
        __syncthreads();
    }
    if (i < NN) rowptr[i] = tmp[tid] - v;          // exclusive within block
    if (tid == 255) bsum[blockIdx.x] = tmp[255];   // block total
}

__global__ __launch_bounds__(512) void k_scan2(int* __restrict__ bsum,
                                               int* __restrict__ bsumoff) {
    __shared__ int tmp[512];
    int tid = threadIdx.x;
    int v = (tid < NB1) ? bsum[tid] : 0;
    tmp[tid] = v;
    __syncthreads();
    #pragma unroll
    for (int d = 1; d < 512; d <<= 1) {
        int t = (tid >= d) ? tmp[tid - d] : 0;
        __syncthreads();
        tmp[tid] += t;
        __syncthreads();
    }
    if (tid < NB1) bsumoff[tid] = tmp[tid] - v;    // exclusive block offsets
}

__global__ __launch_bounds__(256) void k_scan3(int* __restrict__ rowptr,
                                               const int* __restrict__ bsumoff,
                                               int* __restrict__ cursor) {
    int i = blockIdx.x * 256 + threadIdx.x;
    if (i < NN) {
        int rp = rowptr[i] + bsumoff[blockIdx.x];
        rowptr[i] = rp;
        cursor[i] = rp;   // cursor doubles as write position (saves a read in fill)
    }
}

// ---------------- fill CSR: sv[pos] = (src, norm) ----------------
__global__ __launch_bounds__(256) void k_fill(const int* __restrict__ rowi,
                                              const int* __restrict__ coli,
                                              const float* __restrict__ ew,
                                              const float* __restrict__ deg,
                                              int* __restrict__ cursor,
                                              int2* __restrict__ sv) {
    int e = blockIdx.x * 256 + threadIdx.x;
    if (e < EE) {
        int r = rowi[e], c = coli[e];
        float w = ew[e];
        float dr = deg[r], dc = deg[c];
        float norm = (dr > 0.f ? rsqrtf(dr) : 0.f) * w * (dc > 0.f ? rsqrtf(dc) : 0.f);
        int pos = atomicAdd(&cursor[c], 1);
        sv[pos] = make_int2(r, __float_as_int(norm));
    }
}

// ---------------- LN + ReLU + GEMM via MFMA (h bf16 = relu(LN(x)) @ W^T) ----
// LDS fragment-ordered layouts:
//   sA[t(4)][row(64)][k32(32)] bf16  (16 KB)  -- A frag read = 64 consecutive 16B
//   sW[t(4)][n(128)][k32(32)]  bf16  (32 KB)  -- B frag read = 64 consecutive 16B
__global__ __launch_bounds__(256) void k_ln_gemm(const float* __restrict__ x,
                                                 const float* __restrict__ gamma,
                                                 const float* __restrict__ beta,
                                                 const float* __restrict__ W,
                                                 unsigned short* __restrict__ h) {
    __shared__ unsigned short sW[4 * 128 * 32];
    __shared__ unsigned short sA[4 * 64 * 32];

    int t = threadIdx.x;
    int lane = t & 63;
    int wv = t >> 6;
    int row0 = blockIdx.x * 64;

    // Stage W as bf16: panel p = (n, tt) covers W[n][tt*32 .. +32)
    for (int p = t; p < 512; p += 256) {
        int n = p >> 2, tt = p & 3;
        const float* src = &W[n * 128 + tt * 32];
        unsigned int* dst = (unsigned int*)&sW[tt * 4096 + n * 32];
        #pragma unroll
        for (int q = 0; q < 8; ++q) {
            float4 v = *(const float4*)&src[q * 4];
            dst[q * 2 + 0] = (unsigned)f2bf(v.x) | ((unsigned)f2bf(v.y) << 16);
            dst[q * 2 + 1] = (unsigned)f2bf(v.z) | ((unsigned)f2bf(v.w) << 16);
        }
    }

    // LayerNorm + ReLU: wave wv owns rows wv*16..wv*16+15; lane holds k=2*lane,2*lane+1
    int lane2 = lane * 2;
    float g0 = gamma[lane2], g1 = gamma[lane2 + 1];
    float be0 = beta[lane2],  be1 = beta[lane2 + 1];
    for (int i = 0; i < 16; ++i) {
        int r = wv * 16 + i;
        int row = row0 + r;
        float2 v = make_float2(0.f, 0.f);
        if (row < NN) v = *(const float2*)&x[(size_t)row * FDIM + lane2];
        float s  = v.x + v.y;
        float sq = v.x * v.x + v.y * v.y;
        #pragma unroll
        for (int d = 1; d < 64; d <<= 1) {
            s  += __shfl_xor(s, d, 64);
            sq += __shfl_xor(sq, d, 64);
        }
        float mean = s * (1.0f / 128.0f);
        float var  = sq * (1.0f / 128.0f) - mean * mean;
        float rstd = rsqrtf(var + EPS);
        float xn0 = fmaxf((v.x - mean) * rstd * g0 + be0, 0.f);
        float xn1 = fmaxf((v.y - mean) * rstd * g1 + be1, 0.f);
        if (row >= NN) { xn0 = 0.f; xn1 = 0.f; }
        // k = lane2 -> panel tt = lane>>4, offset k&31 (even -> 4B aligned)
        *(unsigned int*)&sA[(lane >> 4) * 2048 + r * 32 + (lane2 & 31)] =
            (unsigned)f2bf(xn0) | ((unsigned)f2bf(xn1) << 16);
    }
    __syncthreads();

    // MFMA: wave computes 16 rows x 128 cols = 8 tiles of 16x16, K=128 in 4 steps
    f32x4 acc[8];
    #pragma unroll
    for (int j = 0; j < 8; ++j) acc[j] = (f32x4){0.f, 0.f, 0.f, 0.f};
    int arow = wv * 16 + (lane & 15);
    int kg = (lane >> 4) * 8;
    #pragma unroll
    for (int tt = 0; tt < 4; ++tt) {
        s16x8 a = *(const s16x8*)&sA[tt * 2048 + arow * 32 + kg];
        #pragma unroll
        for (int j = 0; j < 8; ++j) {
            s16x8 b = *(const s16x8*)&sW[tt * 4096 + (j * 16 + (lane & 15)) * 32 + kg];
            acc[j] = __builtin_amdgcn_mfma_f32_16x16x32_bf16(a, b, acc[j], 0, 0, 0);
        }
    }

    // C/D layout (m89-verified): col = lane&15, row = (lane>>4)*4 + i
    int orow = row0 + wv * 16 + (lane >> 4) * 4;
    int ocol = lane & 15;
    #pragma unroll
    for (int j = 0; j < 8; ++j) {
        #pragma unroll
        for (int i = 0; i < 4; ++i) {
            int g = orow + i;
            if (g < NN) h[(size_t)g * FDIM + j * 16 + ocol] = f2bf(acc[j][i]);
        }
    }
}

// ---------------- gather: one wave per destination node (bf16 h) ------------
__global__ __launch_bounds__(256) void k_gather(const unsigned short* __restrict__ h,
                                                const float* __restrict__ deg,
                                                const int* __restrict__ rowptr,
                                                const int* __restrict__ cnt,
                                                const int2* __restrict__ sv,
                                                const float* __restrict__ b,
                                                float* __restrict__ out) {
    int wv = threadIdx.x >> 6;
    int lane = threadIdx.x & 63;
    int n = blockIdx.x * 4 + wv;
    if (n >= NN) return;

    int f0 = lane * 2;
    float d = deg[n];
    float inv = d > 0.f ? 1.0f / d : 0.f;   // self-loop: dinv * 1.0 * dinv
    unsigned int hv = *(const unsigned int*)&h[(size_t)n * FDIM + f0];
    float accx = __uint_as_float(hv << 16) * inv;
    float accy = __uint_as_float(hv & 0xFFFF0000u) * inv;

    int start = rowptr[n];
    int end = start + cnt[n];
    for (int j = start; j < end; ++j) {
        int2 s = sv[j];                               // wave-uniform broadcast load
        float v = __int_as_float(s.y);
        unsigned int hs = *(const unsigned int*)&h[(size_t)s.x * FDIM + f0];
        accx = fmaf(__uint_as_float(hs << 16), v, accx);
        accy = fmaf(__uint_as_float(hs & 0xFFFF0000u), v, accy);
    }
    float2 bv = *(const float2*)&b[f0];
    *(float2*)&out[(size_t)n * FDIM + f0] = make_float2(accx + bv.x, accy + bv.y);
}

extern "C" void kernel_launch(void* const* d_in, const int* in_sizes, int n_in,
                              void* d_out, int out_size, void* d_ws, size_t ws_size,
                              hipStream_t stream) {
    const float* x     = (const float*)d_in[0];
    const int*   ei    = (const int*)d_in[1];    // [2,E]: rows at ei, cols at ei+EE
    const float* ew    = (const float*)d_in[2];
    const float* gamma = (const float*)d_in[3];
    const float* beta  = (const float*)d_in[4];
    const float* W     = (const float*)d_in[5];
    const float* b     = (const float*)d_in[6];
    float* out = (float*)d_out;

    // workspace layout (~40 MB total; round-4 run proved ws_size >= 66 MB)
    char* p = (char*)d_ws;
    size_t off = 0;
    unsigned short* h = (unsigned short*)(p + off); off += (size_t)NN * FDIM * sizeof(unsigned short); // 25.6 MB
    float* deg    = (float*)(p + off); off += (size_t)NN * sizeof(float);
    int*   cnt    = (int*)  (p + off); off += (size_t)NN * sizeof(int);
    int*   cursor = (int*)  (p + off); off += (size_t)NN * sizeof(int);
    int*   rowptr = (int*)  (p + off); off += (size_t)NN * sizeof(int) + 16;
    int*   bsum   = (int*)  (p + off); off += 512 * sizeof(int);
    int*   bsumof = (int*)  (p + off); off += 512 * sizeof(int);
    int2*  sv     = (int2*) (p + off); off += (size_t)EE * sizeof(int2);         // 12.8 MB
    (void)off; (void)ws_size;

    hipLaunchKernelGGL(k_deg_init, dim3(NB1), dim3(256), 0, stream, deg, cnt);
    hipLaunchKernelGGL(k_deg_acc, dim3((EE + 255) / 256), dim3(256), 0, stream,
                       ei + EE, ew, deg, cnt);
    hipLaunchKernelGGL(k_ln_gemm, dim3((NN + 63) / 64), dim3(256), 0, stream,
                       x, gamma, beta, W, h);
    hipLaunchKernelGGL(k_scan1, dim3(NB1), dim3(256), 0, stream, cnt, rowptr, bsum);
    hipLaunchKernelGGL(k_scan2, dim3(1), dim3(512), 0, stream, bsum, bsumof);
    hipLaunchKernelGGL(k_scan3, dim3(NB1), dim3(256), 0, stream, rowptr, bsumof, cursor);
    hipLaunchKernelGGL(k_fill, dim3((EE + 255) / 256), dim3(256), 0, stream,
                       ei, ei + EE, ew, deg, cursor, sv);
    hipLaunchKernelGGL(k_gather, dim3((NN + 3) / 4), dim3(256), 0, stream,
                       h, deg, rowptr, cnt, sv, b, out);
}

// Round 13
// 419.396 us; speedup vs baseline: 7.1949x; 1.2937x over previous
//
#include <hip/hip_runtime.h>

// Problem constants (match reference)
#define NN 100000
#define EE 1600000
#define FDIM 128
#define EPS 1e-5f

#define NB1 ((NN + 255) / 256)   // 391 blocks for per-node scan

typedef __attribute__((ext_vector_type(8))) short s16x8;   // 8 bf16 (4 VGPRs)
typedef __attribute__((ext_vector_type(4))) float f32x4;   // MFMA accumulator

__device__ __forceinline__ unsigned short f2bf(float f) {   // RNE f32->bf16
    unsigned int u = __float_as_uint(f);
    unsigned int r = u + 0x7FFFu + ((u >> 16) & 1u);
    return (unsigned short)(r >> 16);
}
__device__ __forceinline__ float bf_lo(unsigned int u) { return __uint_as_float(u << 16); }
__device__ __forceinline__ float bf_hi(unsigned int u) { return __uint_as_float(u & 0xFFFF0000u); }

// ---------------- packed degree init ----------------
__global__ __launch_bounds__(256) void k_deg0(unsigned long long* __restrict__ pk) {
    int i = blockIdx.x * 256 + threadIdx.x;
    if (i < NN) pk[i] = 0ULL;
}

// ---------------- degree+count in ONE 64-bit atomic per edge ----------------
// high 32 bits: in-degree count; low 32 bits: fixed-point (2^-20) sum of ew
__global__ __launch_bounds__(256) void k_deg_acc(const int* __restrict__ col,
                                                 const float* __restrict__ ew,
                                                 unsigned long long* __restrict__ pk) {
    int e = blockIdx.x * 256 + threadIdx.x;
    if (e < EE) {
        unsigned q = (unsigned)(ew[e] * 1048576.0f + 0.5f);
        atomicAdd(&pk[col[e]], (1ULL << 32) | (unsigned long long)q);
    }
}

// ---------------- prefix scan (3 kernels) ----------------
__global__ __launch_bounds__(256) void k_scan1(const unsigned long long* __restrict__ pk,
                                               int* __restrict__ rowptr,
                                               int* __restrict__ bsum) {
    __shared__ int tmp[256];
    int tid = threadIdx.x;
    int i = blockIdx.x * 256 + tid;
    int v = (i < NN) ? (int)(pk[i] >> 32) : 0;
    tmp[tid] = v;
    __syncthreads();
    #pragma unroll
    for (int d = 1; d < 256; d <<= 1) {
        int t = (tid >= d) ? tmp[tid - d] : 0;
        __syncthreads();
        tmp[tid] += t;
        __syncthreads();
    }
    if (i < NN) rowptr[i] = tmp[tid] - v;          // exclusive within block
    if (tid == 255) bsum[blockIdx.x] = tmp[255];   // block total
}

__global__ __launch_bounds__(512) void k_scan2(int* __restrict__ bsum,
                                               int* __restrict__ bsumoff) {
    __shared__ int tmp[512];
    int tid = threadIdx.x;
    int v = (tid < NB1) ? bsum[tid] : 0;
    tmp[tid] = v;
    __syncthreads();
    #pragma unroll
    for (int d = 1; d < 512; d <<= 1) {
        int t = (tid >= d) ? tmp[tid - d] : 0;
        __syncthreads();
        tmp[tid] += t;
        __syncthreads();
    }
    if (tid < NB1) bsumoff[tid] = tmp[tid] - v;    // exclusive block offsets
}

// finalize rowptr, init cursor, and compute dinv = rsqrt(1 + weighted_deg)
__global__ __launch_bounds__(256) void k_scan3(int* __restrict__ rowptr,
                                               const int* __restrict__ bsumoff,
                                               int* __restrict__ cursor,
                                               const unsigned long long* __restrict__ pk,
                                               float* __restrict__ dinv) {
    int i = blockIdx.x * 256 + threadIdx.x;
    if (i < NN) {
        int rp = rowptr[i] + bsumoff[blockIdx.x];
        rowptr[i] = rp;
        cursor[i] = rp;
        float deg = 1.0f + (float)(unsigned)(pk[i] & 0xFFFFFFFFu) * (1.0f / 1048576.0f);
        dinv[i] = rsqrtf(deg);   // deg >= 1 always (self-loop)
    }
}

// ---------------- fill CSR: sv[pos] = (src, raw weight) — no deg reads ------
__global__ __launch_bounds__(256) void k_fill(const int* __restrict__ rowi,
                                              const int* __restrict__ coli,
                                              const float* __restrict__ ew,
                                              int* __restrict__ cursor,
                                              int2* __restrict__ sv) {
    int e = blockIdx.x * 256 + threadIdx.x;
    if (e < EE) {
        int pos = atomicAdd(&cursor[coli[e]], 1);
        sv[pos] = make_int2(rowi[e], __float_as_int(ew[e]));
    }
}

// ---------------- LN + ReLU + GEMM via MFMA (h bf16 = relu(LN(x)) @ W^T) ----
// LDS fragment-ordered layouts:
//   sA[t(4)][row(64)][k32(32)] bf16  (16 KB)  -- A frag read = 64 consecutive 16B
//   sW[t(4)][n(128)][k32(32)]  bf16  (32 KB)  -- B frag read = 64 consecutive 16B
__global__ __launch_bounds__(256) void k_ln_gemm(const float* __restrict__ x,
                                                 const float* __restrict__ gamma,
                                                 const float* __restrict__ beta,
                                                 const float* __restrict__ W,
                                                 unsigned short* __restrict__ h) {
    __shared__ unsigned short sW[4 * 128 * 32];
    __shared__ unsigned short sA[4 * 64 * 32];

    int t = threadIdx.x;
    int lane = t & 63;
    int wv = t >> 6;
    int row0 = blockIdx.x * 64;

    // Stage W as bf16: panel p = (n, tt) covers W[n][tt*32 .. +32)
    for (int p = t; p < 512; p += 256) {
        int n = p >> 2, tt = p & 3;
        const float* src = &W[n * 128 + tt * 32];
        unsigned int* dst = (unsigned int*)&sW[tt * 4096 + n * 32];
        #pragma unroll
        for (int q = 0; q < 8; ++q) {
            float4 v = *(const float4*)&src[q * 4];
            dst[q * 2 + 0] = (unsigned)f2bf(v.x) | ((unsigned)f2bf(v.y) << 16);
            dst[q * 2 + 1] = (unsigned)f2bf(v.z) | ((unsigned)f2bf(v.w) << 16);
        }
    }

    // LayerNorm + ReLU: wave wv owns rows wv*16..wv*16+15; lane holds k=2*lane,2*lane+1
    int lane2 = lane * 2;
    float g0 = gamma[lane2], g1 = gamma[lane2 + 1];
    float be0 = beta[lane2],  be1 = beta[lane2 + 1];
    for (int i = 0; i < 16; ++i) {
        int r = wv * 16 + i;
        int row = row0 + r;
        float2 v = make_float2(0.f, 0.f);
        if (row < NN) v = *(const float2*)&x[(size_t)row * FDIM + lane2];
        float s  = v.x + v.y;
        float sq = v.x * v.x + v.y * v.y;
        #pragma unroll
        for (int d = 1; d < 64; d <<= 1) {
            s  += __shfl_xor(s, d, 64);
            sq += __shfl_xor(sq, d, 64);
        }
        float mean = s * (1.0f / 128.0f);
        float var  = sq * (1.0f / 128.0f) - mean * mean;
        float rstd = rsqrtf(var + EPS);
        float xn0 = fmaxf((v.x - mean) * rstd * g0 + be0, 0.f);
        float xn1 = fmaxf((v.y - mean) * rstd * g1 + be1, 0.f);
        if (row >= NN) { xn0 = 0.f; xn1 = 0.f; }
        // k = lane2 -> panel tt = lane>>4, offset k&31 (even -> 4B aligned)
        *(unsigned int*)&sA[(lane >> 4) * 2048 + r * 32 + (lane2 & 31)] =
            (unsigned)f2bf(xn0) | ((unsigned)f2bf(xn1) << 16);
    }
    __syncthreads();

    // MFMA: wave computes 16 rows x 128 cols = 8 tiles of 16x16, K=128 in 4 steps
    f32x4 acc[8];
    #pragma unroll
    for (int j = 0; j < 8; ++j) acc[j] = (f32x4){0.f, 0.f, 0.f, 0.f};
    int arow = wv * 16 + (lane & 15);
    int kg = (lane >> 4) * 8;
    #pragma unroll
    for (int tt = 0; tt < 4; ++tt) {
        s16x8 a = *(const s16x8*)&sA[tt * 2048 + arow * 32 + kg];
        #pragma unroll
        for (int j = 0; j < 8; ++j) {
            s16x8 b = *(const s16x8*)&sW[tt * 4096 + (j * 16 + (lane & 15)) * 32 + kg];
            acc[j] = __builtin_amdgcn_mfma_f32_16x16x32_bf16(a, b, acc[j], 0, 0, 0);
        }
    }

    // C/D layout (m89-verified): col = lane&15, row = (lane>>4)*4 + i
    int orow = row0 + wv * 16 + (lane >> 4) * 4;
    int ocol = lane & 15;
    #pragma unroll
    for (int j = 0; j < 8; ++j) {
        #pragma unroll
        for (int i = 0; i < 4; ++i) {
            int g = orow + i;
            if (g < NN) h[(size_t)g * FDIM + j * 16 + ocol] = f2bf(acc[j][i]);
        }
    }
}

// ---------------- gather v2: shfl-broadcast + 4-wide MLP --------------------
// out[n] = dinv_c * ( sum_e (dinv[r]*w) * h[r]  +  dinv_c * h[n] ) + b
__global__ __launch_bounds__(256) void k_gather(const unsigned short* __restrict__ h,
                                                const float* __restrict__ dinv,
                                                const int* __restrict__ rowptr,
                                                const unsigned long long* __restrict__ pk,
                                                const int2* __restrict__ sv,
                                                const float* __restrict__ b,
                                                float* __restrict__ out) {
    int wv = threadIdx.x >> 6;
    int lane = threadIdx.x & 63;
    int n = blockIdx.x * 4 + wv;
    if (n >= NN) return;

    int f0 = lane * 2;
    float dc = dinv[n];
    unsigned int hv = *(const unsigned int*)&h[(size_t)n * FDIM + f0];
    float accx = bf_lo(hv) * dc;      // self-loop term (will be scaled by dc at end)
    float accy = bf_hi(hv) * dc;

    int start = rowptr[n];
    int end = start + (int)(pk[n] >> 32);

    for (int base = start; base < end; base += 64) {
        int idx = base + lane;
        bool val = idx < end;
        int2 s = sv[val ? idx : start];                 // coalesced 512B per chunk
        float wn = val ? dinv[s.x] * __int_as_float(s.y) : 0.f;  // per-lane, parallel
        int m = min(64, end - base);
        int j = 0;
        for (; j + 3 < m; j += 4) {                     // register-only broadcasts ->
            int   r0 = __shfl(s.x, j, 64),  r1 = __shfl(s.x, j + 1, 64);
            int   r2 = __shfl(s.x, j + 2, 64), r3 = __shfl(s.x, j + 3, 64);
            float w0 = __shfl(wn, j, 64),   w1 = __shfl(wn, j + 1, 64);
            float w2 = __shfl(wn, j + 2, 64), w3 = __shfl(wn, j + 3, 64);
            unsigned int a0 = *(const unsigned int*)&h[(size_t)r0 * FDIM + f0];  // 4 loads
            unsigned int a1 = *(const unsigned int*)&h[(size_t)r1 * FDIM + f0];  // in flight
            unsigned int a2 = *(const unsigned int*)&h[(size_t)r2 * FDIM + f0];
            unsigned int a3 = *(const unsigned int*)&h[(size_t)r3 * FDIM + f0];
            accx = fmaf(bf_lo(a0), w0, accx); accy = fmaf(bf_hi(a0), w0, accy);
            accx = fmaf(bf_lo(a1), w1, accx); accy = fmaf(bf_hi(a1), w1, accy);
            accx = fmaf(bf_lo(a2), w2, accx); accy = fmaf(bf_hi(a2), w2, accy);
            accx = fmaf(bf_lo(a3), w3, accx); accy = fmaf(bf_hi(a3), w3, accy);
        }
        for (; j < m; ++j) {
            int   rj = __shfl(s.x, j, 64);
            float wj = __shfl(wn, j, 64);
            unsigned int aj = *(const unsigned int*)&h[(size_t)rj * FDIM + f0];
            accx = fmaf(bf_lo(aj), wj, accx); accy = fmaf(bf_hi(aj), wj, accy);
        }
    }
    float2 bv = *(const float2*)&b[f0];
    *(float2*)&out[(size_t)n * FDIM + f0] =
        make_float2(fmaf(accx, dc, bv.x), fmaf(accy, dc, bv.y));
}

extern "C" void kernel_launch(void* const* d_in, const int* in_sizes, int n_in,
                              void* d_out, int out_size, void* d_ws, size_t ws_size,
                              hipStream_t stream) {
    const float* x     = (const float*)d_in[0];
    const int*   ei    = (const int*)d_in[1];    // [2,E]: rows at ei, cols at ei+EE
    const float* ew    = (const float*)d_in[2];
    const float* gamma = (const float*)d_in[3];
    const float* beta  = (const float*)d_in[4];
    const float* W     = (const float*)d_in[5];
    const float* b     = (const float*)d_in[6];
    float* out = (float*)d_out;

    // workspace layout (~41 MB total; ws proved >= 66 MB in round 3)
    char* p = (char*)d_ws;
    size_t off = 0;
    unsigned short* h = (unsigned short*)(p + off); off += (size_t)NN * FDIM * sizeof(unsigned short); // 25.6 MB
    unsigned long long* pk = (unsigned long long*)(p + off); off += (size_t)NN * sizeof(unsigned long long); // 0.8 MB
    float* dinv   = (float*)(p + off); off += (size_t)NN * sizeof(float);
    int*   cursor = (int*)  (p + off); off += (size_t)NN * sizeof(int);
    int*   rowptr = (int*)  (p + off); off += (size_t)NN * sizeof(int) + 16;
    int*   bsum   = (int*)  (p + off); off += 512 * sizeof(int);
    int*   bsumof = (int*)  (p + off); off += 512 * sizeof(int);
    int2*  sv     = (int2*) (p + off); off += (size_t)EE * sizeof(int2);         // 12.8 MB
    (void)off; (void)ws_size;

    hipLaunchKernelGGL(k_deg0, dim3(NB1), dim3(256), 0, stream, pk);
    hipLaunchKernelGGL(k_deg_acc, dim3((EE + 255) / 256), dim3(256), 0, stream,
                       ei + EE, ew, pk);
    hipLaunchKernelGGL(k_ln_gemm, dim3((NN + 63) / 64), dim3(256), 0, stream,
                       x, gamma, beta, W, h);
    hipLaunchKernelGGL(k_scan1, dim3(NB1), dim3(256), 0, stream, pk, rowptr, bsum);
    hipLaunchKernelGGL(k_scan2, dim3(1), dim3(512), 0, stream, bsum, bsumof);
    hipLaunchKernelGGL(k_scan3, dim3(NB1), dim3(256), 0, stream, rowptr, bsumof, cursor, pk, dinv);
    hipLaunchKernelGGL(k_fill, dim3((EE + 255) / 256), dim3(256), 0, stream,
                       ei, ei + EE, ew, cursor, sv);
    hipLaunchKernelGGL(k_gather, dim3((NN + 3) / 4), dim3(256), 0, stream,
                       h, dinv, rowptr, pk, sv, b, out);
}

// Round 14
// 351.033 us; speedup vs baseline: 8.5961x; 1.1947x over previous
//
#include <hip/hip_runtime.h>

// Problem constants (match reference)
#define NN 100000
#define EE 1600000
#define FDIM 128
#define EPS 1e-5f

#define NB1 ((NN + 255) / 256)   // 391 blocks for per-node scan

typedef __attribute__((ext_vector_type(8))) short s16x8;   // 8 bf16 (4 VGPRs)
typedef __attribute__((ext_vector_type(4))) float f32x4;   // MFMA accumulator

__device__ __forceinline__ unsigned short f2bf(float f) {   // RNE f32->bf16
    unsigned int u = __float_as_uint(f);
    unsigned int r = u + 0x7FFFu + ((u >> 16) & 1u);
    return (unsigned short)(r >> 16);
}
__device__ __forceinline__ float bf_lo(unsigned int u) { return __uint_as_float(u << 16); }
__device__ __forceinline__ float bf_hi(unsigned int u) { return __uint_as_float(u & 0xFFFF0000u); }

// ---------------- packed degree init ----------------
__global__ __launch_bounds__(256) void k_deg0(unsigned long long* __restrict__ pk) {
    int i = blockIdx.x * 256 + threadIdx.x;
    if (i < NN) pk[i] = 0ULL;
}

// ---------- degree+count in ONE 64-bit atomic per edge; emit edge position --
// high 32 bits: in-degree count; low 32 bits: fixed-point (2^-20) sum of ew.
// The returned old count IS this edge's within-destination sequence number.
__global__ __launch_bounds__(256) void k_deg_acc(const int* __restrict__ col,
                                                 const float* __restrict__ ew,
                                                 unsigned long long* __restrict__ pk,
                                                 int* __restrict__ epos) {
    int e = blockIdx.x * 256 + threadIdx.x;
    if (e < EE) {
        unsigned q = (unsigned)(ew[e] * 1048576.0f + 0.5f);
        unsigned long long old = atomicAdd(&pk[col[e]], (1ULL << 32) | (unsigned long long)q);
        epos[e] = (int)(old >> 32);
    }
}

// ---------------- prefix scan (3 kernels) ----------------
__global__ __launch_bounds__(256) void k_scan1(const unsigned long long* __restrict__ pk,
                                               int* __restrict__ rowptr,
                                               int* __restrict__ bsum) {
    __shared__ int tmp[256];
    int tid = threadIdx.x;
    int i = blockIdx.x * 256 + tid;
    int v = (i < NN) ? (int)(pk[i] >> 32) : 0;
    tmp[tid] = v;
    __syncthreads();
    #pragma unroll
    for (int d = 1; d < 256; d <<= 1) {
        int t = (tid >= d) ? tmp[tid - d] : 0;
        __syncthreads();
        tmp[tid] += t;
        __syncthreads();
    }
    if (i < NN) rowptr[i] = tmp[tid] - v;          // exclusive within block
    if (tid == 255) bsum[blockIdx.x] = tmp[255];   // block total
}

__global__ __launch_bounds__(512) void k_scan2(int* __restrict__ bsum,
                                               int* __restrict__ bsumoff) {
    __shared__ int tmp[512];
    int tid = threadIdx.x;
    int v = (tid < NB1) ? bsum[tid] : 0;
    tmp[tid] = v;
    __syncthreads();
    #pragma unroll
    for (int d = 1; d < 512; d <<= 1) {
        int t = (tid >= d) ? tmp[tid - d] : 0;
        __syncthreads();
        tmp[tid] += t;
        __syncthreads();
    }
    if (tid < NB1) bsumoff[tid] = tmp[tid] - v;    // exclusive block offsets
}

// finalize rowptr and compute dinv = rsqrt(1 + weighted_deg)
__global__ __launch_bounds__(256) void k_scan3(int* __restrict__ rowptr,
                                               const int* __restrict__ bsumoff,
                                               const unsigned long long* __restrict__ pk,
                                               float* __restrict__ dinv) {
    int i = blockIdx.x * 256 + threadIdx.x;
    if (i < NN) {
        rowptr[i] += bsumoff[blockIdx.x];
        float deg = 1.0f + (float)(unsigned)(pk[i] & 0xFFFFFFFFu) * (1.0f / 1048576.0f);
        dinv[i] = rsqrtf(deg);   // deg >= 1 always (self-loop)
    }
}

// ---------------- fill CSR (atomic-free): sv[rowptr[c]+epos[e]] = (r, w) ----
__global__ __launch_bounds__(256) void k_fill(const int* __restrict__ rowi,
                                              const int* __restrict__ coli,
                                              const float* __restrict__ ew,
                                              const int* __restrict__ rowptr,
                                              const int* __restrict__ epos,
                                              int2* __restrict__ sv) {
    int e = blockIdx.x * 256 + threadIdx.x;
    if (e < EE) {
        int pos = rowptr[coli[e]] + epos[e];
        sv[pos] = make_int2(rowi[e], __float_as_int(ew[e]));
    }
}

// ---------------- LN + ReLU + GEMM via MFMA (h bf16 = relu(LN(x)) @ W^T) ----
__global__ __launch_bounds__(256) void k_ln_gemm(const float* __restrict__ x,
                                                 const float* __restrict__ gamma,
                                                 const float* __restrict__ beta,
                                                 const float* __restrict__ W,
                                                 unsigned short* __restrict__ h) {
    __shared__ unsigned short sW[4 * 128 * 32];
    __shared__ unsigned short sA[4 * 64 * 32];

    int t = threadIdx.x;
    int lane = t & 63;
    int wv = t >> 6;
    int row0 = blockIdx.x * 64;

    // Stage W as bf16: panel p = (n, tt) covers W[n][tt*32 .. +32)
    for (int p = t; p < 512; p += 256) {
        int n = p >> 2, tt = p & 3;
        const float* src = &W[n * 128 + tt * 32];
        unsigned int* dst = (unsigned int*)&sW[tt * 4096 + n * 32];
        #pragma unroll
        for (int q = 0; q < 8; ++q) {
            float4 v = *(const float4*)&src[q * 4];
            dst[q * 2 + 0] = (unsigned)f2bf(v.x) | ((unsigned)f2bf(v.y) << 16);
            dst[q * 2 + 1] = (unsigned)f2bf(v.z) | ((unsigned)f2bf(v.w) << 16);
        }
    }

    // LayerNorm + ReLU
    int lane2 = lane * 2;
    float g0 = gamma[lane2], g1 = gamma[lane2 + 1];
    float be0 = beta[lane2],  be1 = beta[lane2 + 1];
    for (int i = 0; i < 16; ++i) {
        int r = wv * 16 + i;
        int row = row0 + r;
        float2 v = make_float2(0.f, 0.f);
        if (row < NN) v = *(const float2*)&x[(size_t)row * FDIM + lane2];
        float s  = v.x + v.y;
        float sq = v.x * v.x + v.y * v.y;
        #pragma unroll
        for (int d = 1; d < 64; d <<= 1) {
            s  += __shfl_xor(s, d, 64);
            sq += __shfl_xor(sq, d, 64);
        }
        float mean = s * (1.0f / 128.0f);
        float var  = sq * (1.0f / 128.0f) - mean * mean;
        float rstd = rsqrtf(var + EPS);
        float xn0 = fmaxf((v.x - mean) * rstd * g0 + be0, 0.f);
        float xn1 = fmaxf((v.y - mean) * rstd * g1 + be1, 0.f);
        if (row >= NN) { xn0 = 0.f; xn1 = 0.f; }
        *(unsigned int*)&sA[(lane >> 4) * 2048 + r * 32 + (lane2 & 31)] =
            (unsigned)f2bf(xn0) | ((unsigned)f2bf(xn1) << 16);
    }
    __syncthreads();

    // MFMA: wave computes 16 rows x 128 cols
    f32x4 acc[8];
    #pragma unroll
    for (int j = 0; j < 8; ++j) acc[j] = (f32x4){0.f, 0.f, 0.f, 0.f};
    int arow = wv * 16 + (lane & 15);
    int kg = (lane >> 4) * 8;
    #pragma unroll
    for (int tt = 0; tt < 4; ++tt) {
        s16x8 a = *(const s16x8*)&sA[tt * 2048 + arow * 32 + kg];
        #pragma unroll
        for (int j = 0; j < 8; ++j) {
            s16x8 b = *(const s16x8*)&sW[tt * 4096 + (j * 16 + (lane & 15)) * 32 + kg];
            acc[j] = __builtin_amdgcn_mfma_f32_16x16x32_bf16(a, b, acc[j], 0, 0, 0);
        }
    }

    // C/D layout: col = lane&15, row = (lane>>4)*4 + i
    int orow = row0 + wv * 16 + (lane >> 4) * 4;
    int ocol = lane & 15;
    #pragma unroll
    for (int j = 0; j < 8; ++j) {
        #pragma unroll
        for (int i = 0; i < 4; ++i) {
            int g = orow + i;
            if (g < NN) h[(size_t)g * FDIM + j * 16 + ocol] = f2bf(acc[j][i]);
        }
    }
}

// ---------------- gather v3: shfl-broadcast + 8-wide MLP --------------------
// out[n] = dc * ( sum_e (dinv[r]*w) * h[r] + dc * h[n] ) + b
__global__ __launch_bounds__(256) void k_gather(const unsigned short* __restrict__ h,
                                                const float* __restrict__ dinv,
                                                const int* __restrict__ rowptr,
                                                const unsigned long long* __restrict__ pk,
                                                const int2* __restrict__ sv,
                                                const float* __restrict__ b,
                                                float* __restrict__ out) {
    int wv = threadIdx.x >> 6;
    int lane = threadIdx.x & 63;
    int n = blockIdx.x * 4 + wv;
    if (n >= NN) return;

    int f0 = lane * 2;
    float dc = dinv[n];
    unsigned int hv = *(const unsigned int*)&h[(size_t)n * FDIM + f0];
    float accx = bf_lo(hv) * dc;      // self-loop term (scaled by dc at end)
    float accy = bf_hi(hv) * dc;

    int start = rowptr[n];
    int end = start + (int)(pk[n] >> 32);

    for (int base = start; base < end; base += 64) {
        int idx = base + lane;
        bool val = idx < end;
        int2 s = sv[val ? idx : start];                 // coalesced chunk load
        float wn = val ? dinv[s.x] * __int_as_float(s.y) : 0.f;
        int m = min(64, end - base);
        int j = 0;
        for (; j + 7 < m; j += 8) {                     // 8 independent gathers
            int ar[8]; float aw[8]; unsigned int av[8];
            #pragma unroll
            for (int q = 0; q < 8; ++q) {
                ar[q] = __shfl(s.x, j + q, 64);
                aw[q] = __shfl(wn, j + q, 64);
            }
            #pragma unroll
            for (int q = 0; q < 8; ++q)
                av[q] = *(const unsigned int*)&h[(size_t)ar[q] * FDIM + f0];
            #pragma unroll
            for (int q = 0; q < 8; ++q) {
                accx = fmaf(bf_lo(av[q]), aw[q], accx);
                accy = fmaf(bf_hi(av[q]), aw[q], accy);
            }
        }
        for (; j + 3 < m; j += 4) {
            int ar[4]; float aw[4]; unsigned int av[4];
            #pragma unroll
            for (int q = 0; q < 4; ++q) {
                ar[q] = __shfl(s.x, j + q, 64);
                aw[q] = __shfl(wn, j + q, 64);
            }
            #pragma unroll
            for (int q = 0; q < 4; ++q)
                av[q] = *(const unsigned int*)&h[(size_t)ar[q] * FDIM + f0];
            #pragma unroll
            for (int q = 0; q < 4; ++q) {
                accx = fmaf(bf_lo(av[q]), aw[q], accx);
                accy = fmaf(bf_hi(av[q]), aw[q], accy);
            }
        }
        for (; j < m; ++j) {
            int   rj = __shfl(s.x, j, 64);
            float wj = __shfl(wn, j, 64);
            unsigned int aj = *(const unsigned int*)&h[(size_t)rj * FDIM + f0];
            accx = fmaf(bf_lo(aj), wj, accx);
            accy = fmaf(bf_hi(aj), wj, accy);
        }
    }
    float2 bv = *(const float2*)&b[f0];
    *(float2*)&out[(size_t)n * FDIM + f0] =
        make_float2(fmaf(accx, dc, bv.x), fmaf(accy, dc, bv.y));
}

extern "C" void kernel_launch(void* const* d_in, const int* in_sizes, int n_in,
                              void* d_out, int out_size, void* d_ws, size_t ws_size,
                              hipStream_t stream) {
    const float* x     = (const float*)d_in[0];
    const int*   ei    = (const int*)d_in[1];    // [2,E]: rows at ei, cols at ei+EE
    const float* ew    = (const float*)d_in[2];
    const float* gamma = (const float*)d_in[3];
    const float* beta  = (const float*)d_in[4];
    const float* W     = (const float*)d_in[5];
    const float* b     = (const float*)d_in[6];
    float* out = (float*)d_out;

    // workspace layout (~46.5 MB; ws proved >= 66 MB in round 3)
    char* p = (char*)d_ws;
    size_t off = 0;
    unsigned short* h = (unsigned short*)(p + off); off += (size_t)NN * FDIM * sizeof(unsigned short); // 25.6 MB
    unsigned long long* pk = (unsigned long long*)(p + off); off += (size_t)NN * sizeof(unsigned long long); // 0.8 MB
    float* dinv   = (float*)(p + off); off += (size_t)NN * sizeof(float);
    int*   rowptr = (int*)  (p + off); off += (size_t)NN * sizeof(int) + 16;
    int*   bsum   = (int*)  (p + off); off += 512 * sizeof(int);
    int*   bsumof = (int*)  (p + off); off += 512 * sizeof(int);
    int*   epos   = (int*)  (p + off); off += (size_t)EE * sizeof(int);          // 6.4 MB
    int2*  sv     = (int2*) (p + off); off += (size_t)EE * sizeof(int2);         // 12.8 MB
    (void)off; (void)ws_size;

    hipLaunchKernelGGL(k_deg0, dim3(NB1), dim3(256), 0, stream, pk);
    hipLaunchKernelGGL(k_deg_acc, dim3((EE + 255) / 256), dim3(256), 0, stream,
                       ei + EE, ew, pk, epos);
    hipLaunchKernelGGL(k_ln_gemm, dim3((NN + 63) / 64), dim3(256), 0, stream,
                       x, gamma, beta, W, h);
    hipLaunchKernelGGL(k_scan1, dim3(NB1), dim3(256), 0, stream, pk, rowptr, bsum);
    hipLaunchKernelGGL(k_scan2, dim3(1), dim3(512), 0, stream, bsum, bsumof);
    hipLaunchKernelGGL(k_scan3, dim3(NB1), dim3(256), 0, stream, rowptr, bsumof, pk, dinv);
    hipLaunchKernelGGL(k_fill, dim3((EE + 255) / 256), dim3(256), 0, stream,
                       ei, ei + EE, ew, rowptr, epos, sv);
    hipLaunchKernelGGL(k_gather, dim3((NN + 3) / 4), dim3(256), 0, stream,
                       h, dinv, rowptr, pk, sv, b, out);
}